// Round 2
// baseline (333.888 us; speedup 1.0000x reference)
//
#include <hip/hip_runtime.h>
#include <math.h>

// Problem constants (from reference setup_inputs)
constexpr int B = 8, C = 64, W = 240, H = 240, N = 2000, M = 8;
constexpr int WH = W * H;
constexpr float MARGIN = 0.5f;
constexpr float EPS = 1e-7f;

// 2000 blocks x 4 waves = 8000 waves; 16000 points -> 2 points/wave.
constexpr int NBLOCKS = 2000;
constexpr int WAVES_PER_BLOCK = 4;

__device__ __forceinline__ float wave_sum64(float v) {
#pragma unroll
    for (int s = 32; s > 0; s >>= 1) v += __shfl_xor(v, s, 64);
    return v;  // all 64 lanes hold the full sum
}

__global__ __launch_bounds__(256) void triplet_partial(
    const float* __restrict__ out1, const float* __restrict__ out2,
    const int2* __restrict__ xy1, const int2* __restrict__ xy2,
    const int2* __restrict__ nm2, float* __restrict__ partial)
{
    const int lane = threadIdx.x & 63;      // = channel c
    const int wave = threadIdx.x >> 6;
    const int gwave = blockIdx.x * WAVES_PER_BLOCK + wave;
    const int nwaves = NBLOCKS * WAVES_PER_BLOCK;

    float acc = 0.0f;

    for (int p = gwave; p < B * N; p += nwaves) {
        const int b = p / N;
        const int n = p - b * N;

        // channel-plane base for this (b, lane): lane = channel
        const float* img1 = out1 + (size_t)(b * C + lane) * WH;
        const float* img2 = out2 + (size_t)(b * C + lane) * WH;

        // ---- f1 ----
        const int2 q1 = xy1[(size_t)b * N + n];
        const float f1 = img1[q1.x * H + q1.y];

        // ---- f2 / positive distance ----
        const int2 q2 = xy2[(size_t)b * N + n];
        const float f2 = img2[q2.x * H + q2.y];
        const float dp = f1 - f2;
        const float pos_dist = sqrtf(wave_sum64(dp * dp) + EPS);

        // ---- negatives: mean over M of sqrt distances ----
        float neg_sum = 0.0f;
#pragma unroll
        for (int j = 0; j < M; ++j) {
            const int2 qn = nm2[(((size_t)b * M + j) * N) + n];
            const float fn = img2[qn.x * H + qn.y];
            const float dn = f1 - fn;
            neg_sum += sqrtf(wave_sum64(dn * dn) + EPS);
        }
        const float neg_mean = neg_sum * (1.0f / M);

        const float v = pos_dist - neg_mean + MARGIN;
        acc += (v > 0.0f) ? v : 0.0f;   // relu
    }

    // acc is wave-uniform (butterfly reduce leaves full sum in all lanes)
    __shared__ float smem[WAVES_PER_BLOCK];
    if (lane == 0) smem[wave] = acc;
    __syncthreads();
    if (threadIdx.x == 0) {
        float s = 0.0f;
#pragma unroll
        for (int i = 0; i < WAVES_PER_BLOCK; ++i) s += smem[i];
        partial[blockIdx.x] = s;
    }
}

__global__ __launch_bounds__(256) void reduce_partials(
    const float* __restrict__ partial, float* __restrict__ out)
{
    float s = 0.0f;
    for (int i = threadIdx.x; i < NBLOCKS; i += 256) s += partial[i];

    __shared__ float smem[256];
    smem[threadIdx.x] = s;
    __syncthreads();
#pragma unroll
    for (int stride = 128; stride > 0; stride >>= 1) {
        if (threadIdx.x < stride) smem[threadIdx.x] += smem[threadIdx.x + stride];
        __syncthreads();
    }
    if (threadIdx.x == 0) out[0] = smem[0] * (1.0f / (B * N));
}

extern "C" void kernel_launch(void* const* d_in, const int* in_sizes, int n_in,
                              void* d_out, int out_size, void* d_ws, size_t ws_size,
                              hipStream_t stream)
{
    const float* out1 = (const float*)d_in[0];
    const float* out2 = (const float*)d_in[1];
    const int2*  xy1  = (const int2*)d_in[2];
    const int2*  xy2  = (const int2*)d_in[3];
    const int2*  nm2  = (const int2*)d_in[4];
    float* out = (float*)d_out;
    float* partial = (float*)d_ws;   // NBLOCKS floats

    triplet_partial<<<NBLOCKS, 256, 0, stream>>>(out1, out2, xy1, xy2, nm2, partial);
    reduce_partials<<<1, 256, 0, stream>>>(partial, out);
}

// Round 3
// 269.805 us; speedup vs baseline: 1.2375x; 1.2375x over previous
//
#include <hip/hip_runtime.h>
#include <math.h>

// Problem constants (from reference setup_inputs)
constexpr int B = 8, C = 64, W = 240, H = 240, N = 2000, M = 8;
constexpr int WH = W * H;               // 57600
constexpr float MARGIN = 0.5f;
constexpr float EPS = 1e-7f;

__device__ __forceinline__ float wave_sum64(float v) {
#pragma unroll
    for (int s = 32; s > 0; s >>= 1) v += __shfl_xor(v, s, 64);
    return v;  // all 64 lanes hold the full sum
}

// ---------------------------------------------------------------------------
// Kernel 1: transpose out2 (b, c, wh) -> (b, wh, c).  Tiles of 64ch x 64pos.
// ---------------------------------------------------------------------------
constexpr int TPOS = 64;                       // positions per tile
constexpr int TBLOCKS = B * (WH / TPOS);       // 8 * 900 = 7200

__global__ __launch_bounds__(256) void transpose_out2(
    const float* __restrict__ src, float* __restrict__ dst)
{
    __shared__ float tile[C][TPOS + 1];        // 64 x 65, pad kills conflicts
    const int bid = blockIdx.x;
    const int b   = bid / (WH / TPOS);
    const int p0  = (bid % (WH / TPOS)) * TPOS;
    const int lane = threadIdx.x & 63;
    const int grp  = threadIdx.x >> 6;         // 0..3

    const float* s = src + (size_t)b * C * WH;
#pragma unroll
    for (int i = 0; i < 16; ++i) {
        const int c = grp + i * 4;
        tile[c][lane] = s[(size_t)c * WH + p0 + lane];   // 256B coalesced
    }
    __syncthreads();
    float* d = dst + ((size_t)b * WH + p0) * C;
#pragma unroll
    for (int i = 0; i < 16; ++i) {
        const int tp = grp + i * 4;
        d[(size_t)tp * C + lane] = tile[lane][tp];       // 256B coalesced
    }
}

// ---------------------------------------------------------------------------
// Kernel 2: gather + triplet math.  1 point per wave, 16000 waves.
// ---------------------------------------------------------------------------
constexpr int GW = 4;                          // waves per block
constexpr int GBLOCKS = (B * N) / GW;          // 4000

__global__ __launch_bounds__(256) void triplet_gather(
    const float* __restrict__ out1, const float* __restrict__ out2T,
    const int2* __restrict__ xy1, const int2* __restrict__ xy2,
    const int2* __restrict__ nm2, float* __restrict__ partial)
{
    const int lane = threadIdx.x & 63;         // = channel
    const int wave = threadIdx.x >> 6;
    const int p = blockIdx.x * GW + wave;      // 0..15999
    const int b = p / N, n = p - b * N;

    // f1: direct strided gather from out1 (not transposed)
    const int2 q1 = xy1[(size_t)b * N + n];
    const float f1 = out1[(size_t)(b * C + lane) * WH + q1.x * H + q1.y];

    const float* base2 = out2T + (size_t)b * WH * C;

    // f2: contiguous 256B vector from transposed out2
    const int2 q2 = xy2[(size_t)b * N + n];
    const float f2 = base2[(size_t)(q2.x * H + q2.y) * C + lane];
    const float dp = f1 - f2;
    const float pos_dist = sqrtf(wave_sum64(dp * dp) + EPS);

    float neg_sum = 0.0f;
#pragma unroll
    for (int j = 0; j < M; ++j) {
        const int2 qn = nm2[(((size_t)b * M + j) * N) + n];
        const float fn = base2[(size_t)(qn.x * H + qn.y) * C + lane];
        const float dn = f1 - fn;
        neg_sum += sqrtf(wave_sum64(dn * dn) + EPS);
    }

    const float v = pos_dist - neg_sum * (1.0f / M) + MARGIN;
    const float res = (v > 0.0f) ? v : 0.0f;

    __shared__ float sm[GW];
    if (lane == 0) sm[wave] = res;
    __syncthreads();
    if (threadIdx.x == 0) {
        float s = 0.0f;
#pragma unroll
        for (int i = 0; i < GW; ++i) s += sm[i];
        partial[blockIdx.x] = s;
    }
}

// ---------------------------------------------------------------------------
// Fallback direct kernel (used only if ws too small for the transpose buffer)
// ---------------------------------------------------------------------------
constexpr int FBLOCKS = 2000, FW = 4;

__global__ __launch_bounds__(256) void triplet_direct(
    const float* __restrict__ out1, const float* __restrict__ out2,
    const int2* __restrict__ xy1, const int2* __restrict__ xy2,
    const int2* __restrict__ nm2, float* __restrict__ partial)
{
    const int lane = threadIdx.x & 63;
    const int wave = threadIdx.x >> 6;
    const int gwave = blockIdx.x * FW + wave;
    float acc = 0.0f;
    for (int p = gwave; p < B * N; p += FBLOCKS * FW) {
        const int b = p / N, n = p - b * N;
        const float* img1 = out1 + (size_t)(b * C + lane) * WH;
        const float* img2 = out2 + (size_t)(b * C + lane) * WH;
        const int2 q1 = xy1[(size_t)b * N + n];
        const float f1 = img1[q1.x * H + q1.y];
        const int2 q2 = xy2[(size_t)b * N + n];
        const float f2 = img2[q2.x * H + q2.y];
        const float dp = f1 - f2;
        const float pos_dist = sqrtf(wave_sum64(dp * dp) + EPS);
        float neg_sum = 0.0f;
#pragma unroll
        for (int j = 0; j < M; ++j) {
            const int2 qn = nm2[(((size_t)b * M + j) * N) + n];
            const float fn = img2[qn.x * H + qn.y];
            const float dn = f1 - fn;
            neg_sum += sqrtf(wave_sum64(dn * dn) + EPS);
        }
        const float v = pos_dist - neg_sum * (1.0f / M) + MARGIN;
        acc += (v > 0.0f) ? v : 0.0f;
    }
    __shared__ float smem[FW];
    if (lane == 0) smem[wave] = acc;
    __syncthreads();
    if (threadIdx.x == 0) {
        float s = 0.0f;
#pragma unroll
        for (int i = 0; i < FW; ++i) s += smem[i];
        partial[blockIdx.x] = s;
    }
}

// ---------------------------------------------------------------------------
// Final reduce over partials
// ---------------------------------------------------------------------------
__global__ __launch_bounds__(256) void reduce_partials(
    const float* __restrict__ partial, int count, float* __restrict__ out)
{
    float s = 0.0f;
    for (int i = threadIdx.x; i < count; i += 256) s += partial[i];
    __shared__ float smem[256];
    smem[threadIdx.x] = s;
    __syncthreads();
#pragma unroll
    for (int stride = 128; stride > 0; stride >>= 1) {
        if (threadIdx.x < stride) smem[threadIdx.x] += smem[threadIdx.x + stride];
        __syncthreads();
    }
    if (threadIdx.x == 0) out[0] = smem[0] * (1.0f / (B * N));
}

extern "C" void kernel_launch(void* const* d_in, const int* in_sizes, int n_in,
                              void* d_out, int out_size, void* d_ws, size_t ws_size,
                              hipStream_t stream)
{
    const float* out1 = (const float*)d_in[0];
    const float* out2 = (const float*)d_in[1];
    const int2*  xy1  = (const int2*)d_in[2];
    const int2*  xy2  = (const int2*)d_in[3];
    const int2*  nm2  = (const int2*)d_in[4];
    float* out = (float*)d_out;

    const size_t tbytes = (size_t)B * WH * C * sizeof(float);   // 118MB
    const size_t need   = tbytes + (size_t)GBLOCKS * sizeof(float);

    if (ws_size >= need) {
        float* out2T   = (float*)d_ws;
        float* partial = (float*)((char*)d_ws + tbytes);
        transpose_out2<<<TBLOCKS, 256, 0, stream>>>(out2, out2T);
        triplet_gather<<<GBLOCKS, 256, 0, stream>>>(out1, out2T, xy1, xy2, nm2, partial);
        reduce_partials<<<1, 256, 0, stream>>>(partial, GBLOCKS, out);
    } else {
        float* partial = (float*)d_ws;                          // 8KB
        triplet_direct<<<FBLOCKS, 256, 0, stream>>>(out1, out2, xy1, xy2, nm2, partial);
        reduce_partials<<<1, 256, 0, stream>>>(partial, FBLOCKS, out);
    }
}